// Round 2
// baseline (266.105 us; speedup 1.0000x reference)
//
#include <hip/hip_runtime.h>
#include <hip/hip_bf16.h>

// diag(triggers * mask) for N=8192: 8192x8192 fp32 output, zeros off-diagonal.
// Harness re-poisons d_out (0xAA) before every timed call -> must write all
// 256 MiB of zeros every launch. Pure HBM-write-bound: floor = 256 MiB /
// ~6.3 TB/s ~= 42 us.
//
// R1 lesson: hipMemsetAsync's rocclr fillBufferAligned runs at only
// ~1.66 TB/s (10% occupancy, undersized grid) -> 161 us, plus a separate
// diag dispatch. Fix: single fused kernel, one float4 store per thread
// (64 lanes x 16 B = 1 KiB/instr, full-line writes -> no RMW fetch),
// diagonal element injected on the rare path.

#define N 8192               // row = flat >> 13, col = flat & 8191
#define VEC_COUNT (size_t)((size_t)N * N / 4)   // 16,777,216 float4 stores

__global__ void fill_diag_kernel(const float* __restrict__ triggers,
                                 const int* __restrict__ mask,
                                 float4* __restrict__ out) {
    size_t v = (size_t)blockIdx.x * blockDim.x + threadIdx.x;  // float4 index
    size_t f = v << 2;                       // flat element index (4-aligned)
    unsigned r = (unsigned)(f >> 13);        // row (constant across the 4 elems)
    unsigned c = (unsigned)(f & (N - 1));    // starting col of this float4
    float4 z = make_float4(0.f, 0.f, 0.f, 0.f);
    unsigned d = r - c;                      // diagonal lands here iff d < 4
    if (d < 4u) {                            // taken by 1 vector in 2048
        ((float*)&z)[d] = triggers[r] * (float)mask[r];
    }
    out[v] = z;
}

extern "C" void kernel_launch(void* const* d_in, const int* in_sizes, int n_in,
                              void* d_out, int out_size, void* d_ws, size_t ws_size,
                              hipStream_t stream) {
    const float* triggers = (const float*)d_in[0];
    const int*   mask     = (const int*)d_in[1];
    float4*      out      = (float4*)d_out;

    // 16M float4 stores / 256 threads = 65,536 blocks -> saturates 256 CUs.
    dim3 grid((unsigned)(VEC_COUNT / 256));
    fill_diag_kernel<<<grid, 256, 0, stream>>>(triggers, mask, out);
}